// Round 6
// baseline (2482.877 us; speedup 1.0000x reference)
//
#include <hip/hip_runtime.h>
#include <hip/hip_bf16.h>

typedef _Float16 half8 __attribute__((ext_vector_type(8)));
typedef float floatx4 __attribute__((ext_vector_type(4)));

__device__ __constant__ float NF4_TAB[16] = {
    -1.0f, -0.6961928009986877f, -0.5250730514526367f, -0.39491748809814453f,
    -0.28444138169288635f, -0.18477343022823334f, -0.09105003625154495f, 0.0f,
    0.07958029955625534f, 0.16093020141124725f, 0.24611230194568634f,
    0.33791524171829224f, 0.44070982933044434f, 0.5626170039176941f,
    0.7229568362236023f, 1.0f};

typedef __attribute__((address_space(3))) void lds_t;
typedef __attribute__((address_space(1))) void gbl_t;

__device__ __forceinline__ void gload16(const void* g, void* l) {
  __builtin_amdgcn_global_load_lds((gbl_t*)g, (lds_t*)l, 16, 0, 0);
}

// ---------------- x f32 -> f16 ----------------
__global__ void cvt_f32_to_f16(const float* __restrict__ in,
                               _Float16* __restrict__ out, int total8) {
  int stride = gridDim.x * blockDim.x;
  for (int i = blockIdx.x * blockDim.x + threadIdx.x; i < total8; i += stride) {
    long e = (long)i * 8;
    const float4* ip = reinterpret_cast<const float4*>(in + e);
    float4 a = ip[0], b = ip[1];
    half8 o;
    o[0] = (_Float16)a.x; o[1] = (_Float16)a.y;
    o[2] = (_Float16)a.z; o[3] = (_Float16)a.w;
    o[4] = (_Float16)b.x; o[5] = (_Float16)b.y;
    o[6] = (_Float16)b.z; o[7] = (_Float16)b.w;
    *reinterpret_cast<half8*>(out + e) = o;
  }
}

// ---------------- NF4 dequant: codes[R,C] + scales[R,C/64] -> f16 [R,C] ----
__global__ void dequant_nf4(const int* __restrict__ codes,
                            const float* __restrict__ scales,
                            _Float16* __restrict__ out,
                            int total8, int C, int CB) {
  __shared__ float lut[16];
  if (threadIdx.x < 16) lut[threadIdx.x] = NF4_TAB[threadIdx.x];
  __syncthreads();
  int stride = gridDim.x * blockDim.x;
  for (int i = blockIdx.x * blockDim.x + threadIdx.x; i < total8; i += stride) {
    long e = (long)i * 8;
    int row = (int)(e / C);
    int col = (int)(e - (long)row * C);
    float sc = scales[row * CB + (col >> 6)];
    const int4* cp = reinterpret_cast<const int4*>(codes + e);
    int4 c0 = cp[0];
    int4 c1 = cp[1];
    half8 o;
    o[0] = (_Float16)(lut[c0.x & 15] * sc);
    o[1] = (_Float16)(lut[c0.y & 15] * sc);
    o[2] = (_Float16)(lut[c0.z & 15] * sc);
    o[3] = (_Float16)(lut[c0.w & 15] * sc);
    o[4] = (_Float16)(lut[c1.x & 15] * sc);
    o[5] = (_Float16)(lut[c1.y & 15] * sc);
    o[6] = (_Float16)(lut[c1.z & 15] * sc);
    o[7] = (_Float16)(lut[c1.w & 15] * sc);
    *reinterpret_cast<half8*>(out + e) = o;
  }
}

// =====================================================================
// 256x256 GEMM, BK=64, 8 waves (2Mx4N), per-wave 128x64 output.
// Quadrant schedule: 4 phases/K-tile, each = one 64x32 C-quadrant x K=64
// (16 MFMA). Reads per phase: 8/4/8/4 ds_read_b128; B-h0 of tile t+1 is
// pre-read in ph3(t) so its drain overlaps Q11's MFMA.
// Staging (2 dbuf, slab-rotated):
//   ph0(t): A(t+1) -> buf(t+1).A  [4 gloads]   (buf(t+1).A free after ph2(t-1))
//   ph3(t): B(t+2) -> buf(t).B    [4 gloads]   (buf(t).B free after ph1(t))
// Ledger (vmcnt, 4 loads/slot, never drains to 0 mid-loop):
//   ph2(t)-end: vmcnt(4) certifies B(t+1) [A(t+1) 4 newer, in flight]
//   ph3(t)-end: vmcnt(4) certifies A(t+1) [B(t+2) 4 newer, in flight]
// Every slot has >= 3 phases from issue to certify (covers HBM latency).
// Block order: 8bm x 8bn super-groups; bid&7 = bn-in-group -> each B
// column-panel is consumed by ONE XCD (L2-resident), A streams from LLC.
// Chunk-XOR swizzle (phys = logical ^ ((row>>1)&3)): 0 bank conflicts.
// EPI: 0 = f16 store; 1 = GH[idx]=silu(GH[idx])*acc (in-place); 2 = f32.
// =====================================================================
template <int K, int N, int EPI>
__global__ __launch_bounds__(512, 2) void gemm256(
    const _Float16* __restrict__ A,
    const _Float16* __restrict__ B,
    _Float16* __restrict__ GH,
    float* __restrict__ OUT) {
  constexpr int NT = K / 64;
  constexpr int NBC = N / 256;
  constexpr int NFULL = NBC / 8;            // full 8-wide bn groups
  constexpr int TAILW = NBC - 8 * NFULL;    // ragged tail width
  constexpr int FULLB = NFULL * 256;        // 32 bm * 8 bn per group
  __shared__ __align__(16) _Float16 lds[2 * 32768];  // 128 KB

  const int t = threadIdx.x;       // 0..511
  const int lane = t & 63;
  const int wave = t >> 6;
  const int wm = wave >> 2;        // 0..1
  const int wn = wave & 3;         // 0..3

  // ---- 2D super-group block mapping (XCD-pinned B panels) ----
  int bm, bn;
  {
    const int bid = blockIdx.x;
    if (bid < FULLB) {
      const int g = bid >> 8;          // group
      const int r = bid & 255;
      bm = r >> 3;
      bn = g * 8 + (r & 7);            // bid&7 == XCD == bn-in-group
    } else if (TAILW > 0) {
      const int r = bid - FULLB;
      bm = r / (TAILW > 0 ? TAILW : 1);
      bn = NFULL * 8 + r % (TAILW > 0 ? TAILW : 1);
    } else {
      bm = 0; bn = 0;  // unreachable
    }
  }

  // ---- staging addresses (linear LDS dest, pre-permuted global src) ----
  const int lc = (t & 3) ^ ((t >> 3) & 3);
  const _Float16* gA = A + ((long)bm * 256 + (t >> 2)) * K + lc * 8;
  const _Float16* gB = B + ((long)bn * 256 + (t >> 2)) * K + lc * 8;
  const long rstep = (long)128 * K;
  const int dst = t * 8;  // f16 units

  // slabs within a buffer (f16 units): A@kk0=0, A@kk1=8192, B@kk0=16384, B@kk1=24576
#define STAGE_SLOT(gp, slab, koff, dbuf)                                   \
  gload16((gp) + (koff), lds + (dbuf) * 32768 + (slab) + dst);             \
  gload16((gp) + (koff) + rstep, lds + (dbuf) * 32768 + (slab) + dst + 4096);

  // ---- fragment read offsets ----
  const int rA = wm * 128 + (lane & 15);
  const int rB = wn * 64 + (lane & 15);
  const int ckA = ((lane >> 4) ^ ((rA >> 1) & 3)) * 8;
  const int ckB = ((lane >> 4) ^ ((rB >> 1) & 3)) * 8;
  const int offA = rA * 32 + ckA;           // + rr*512 (+2048 h1) (+8192 kk1)
  const int offB = 16384 + rB * 32 + ckB;   // + jj*512 (+1024 h1) (+8192 kk1)

  // ---- prologue: B(0),A(0)->buf0; B(1)->buf1; certify B(0)+A(0) ----
  STAGE_SLOT(gB, 16384, 0, 0);  STAGE_SLOT(gB, 24576, 32, 0);   // B(0)
  STAGE_SLOT(gA, 0, 0, 0);      STAGE_SLOT(gA, 8192, 32, 0);    // A(0)
  STAGE_SLOT(gB, 16384, 64, 1); STAGE_SLOT(gB, 24576, 96, 1);   // B(1)
  gA += 64;    // -> tile 1 (ph0(0) stages A(1))
  gB += 128;   // -> tile 2 (ph3(0) stages B(2))
  asm volatile("s_waitcnt vmcnt(4)" ::: "memory");  // B(0),A(0) done; B(1) flying
  __builtin_amdgcn_s_barrier();
  __builtin_amdgcn_sched_barrier(0);

  floatx4 acc[8][4] = {};
  half8 b0[4], b1[4], a[8];

  // pre-read bq0(0) from buf0
#pragma unroll
  for (int jj = 0; jj < 2; ++jj)
#pragma unroll
    for (int kk = 0; kk < 2; ++kk)
      b0[jj * 2 + kk] = *reinterpret_cast<const half8*>(&lds[offB + jj * 512 + kk * 8192]);

  for (int kt = 0; kt < NT; ++kt) {
    const int cb = kt & 1;
    const int sb = cb ^ 1;
    const _Float16* lb = lds + cb * 32768;
    const bool stA = (kt + 1 < NT);
    const bool stB = (kt + 2 < NT);

    // ---- ph0: read aq(h0) x8; stage A(t+1)->sb; Q00 ----
#pragma unroll
    for (int rr = 0; rr < 4; ++rr)
#pragma unroll
      for (int kk = 0; kk < 2; ++kk)
        a[rr * 2 + kk] = *reinterpret_cast<const half8*>(&lb[offA + rr * 512 + kk * 8192]);
    if (stA) { STAGE_SLOT(gA, 0, 0, sb); STAGE_SLOT(gA, 8192, 32, sb); gA += 64; }
    __builtin_amdgcn_s_barrier();
    asm volatile("s_waitcnt lgkmcnt(0)" ::: "memory");
    __builtin_amdgcn_sched_barrier(0);
    __builtin_amdgcn_s_setprio(1);
#pragma unroll
    for (int rr = 0; rr < 4; ++rr)
#pragma unroll
      for (int kk = 0; kk < 2; ++kk)
#pragma unroll
        for (int jj = 0; jj < 2; ++jj)
          acc[rr][jj] = __builtin_amdgcn_mfma_f32_16x16x32_f16(a[rr * 2 + kk], b0[jj * 2 + kk], acc[rr][jj], 0, 0, 0);
    __builtin_amdgcn_s_setprio(0);
    __builtin_amdgcn_s_barrier();
    __builtin_amdgcn_sched_barrier(0);

    // ---- ph1: read bq1 x4; Q01 ----
#pragma unroll
    for (int jj = 0; jj < 2; ++jj)
#pragma unroll
      for (int kk = 0; kk < 2; ++kk)
        b1[jj * 2 + kk] = *reinterpret_cast<const half8*>(&lb[offB + 1024 + jj * 512 + kk * 8192]);
    __builtin_amdgcn_s_barrier();
    asm volatile("s_waitcnt lgkmcnt(0)" ::: "memory");
    __builtin_amdgcn_sched_barrier(0);
    __builtin_amdgcn_s_setprio(1);
#pragma unroll
    for (int rr = 0; rr < 4; ++rr)
#pragma unroll
      for (int kk = 0; kk < 2; ++kk)
#pragma unroll
        for (int jj = 0; jj < 2; ++jj)
          acc[rr][2 + jj] = __builtin_amdgcn_mfma_f32_16x16x32_f16(a[rr * 2 + kk], b1[jj * 2 + kk], acc[rr][2 + jj], 0, 0, 0);
    __builtin_amdgcn_s_setprio(0);
    __builtin_amdgcn_s_barrier();
    __builtin_amdgcn_sched_barrier(0);

    // ---- ph2: read aq(h1) x8; Q10; certify B(t+1) ----
#pragma unroll
    for (int rr = 0; rr < 4; ++rr)
#pragma unroll
      for (int kk = 0; kk < 2; ++kk)
        a[rr * 2 + kk] = *reinterpret_cast<const half8*>(&lb[offA + 2048 + rr * 512 + kk * 8192]);
    __builtin_amdgcn_s_barrier();
    asm volatile("s_waitcnt lgkmcnt(0)" ::: "memory");
    __builtin_amdgcn_sched_barrier(0);
    __builtin_amdgcn_s_setprio(1);
#pragma unroll
    for (int rr = 0; rr < 4; ++rr)
#pragma unroll
      for (int kk = 0; kk < 2; ++kk)
#pragma unroll
        for (int jj = 0; jj < 2; ++jj)
          acc[4 + rr][jj] = __builtin_amdgcn_mfma_f32_16x16x32_f16(a[rr * 2 + kk], b0[jj * 2 + kk], acc[4 + rr][jj], 0, 0, 0);
    __builtin_amdgcn_s_setprio(0);
    if (stA) { asm volatile("s_waitcnt vmcnt(4)" ::: "memory"); }  // B(t+1) done
    __builtin_amdgcn_s_barrier();
    __builtin_amdgcn_sched_barrier(0);

    // ---- ph3: pre-read bq0(t+1) from sb; stage B(t+2)->cb.B; Q11; certify A(t+1) ----
    if (stA) {
      const _Float16* nb = lds + sb * 32768;
#pragma unroll
      for (int jj = 0; jj < 2; ++jj)
#pragma unroll
        for (int kk = 0; kk < 2; ++kk)
          b0[jj * 2 + kk] = *reinterpret_cast<const half8*>(&nb[offB + jj * 512 + kk * 8192]);
    }
    if (stB) { STAGE_SLOT(gB, 16384, 0, cb); STAGE_SLOT(gB, 24576, 32, cb); gB += 64; }
    __builtin_amdgcn_s_barrier();
    __builtin_amdgcn_sched_barrier(0);
    __builtin_amdgcn_s_setprio(1);
#pragma unroll
    for (int rr = 0; rr < 4; ++rr)
#pragma unroll
      for (int kk = 0; kk < 2; ++kk)
#pragma unroll
        for (int jj = 0; jj < 2; ++jj)
          acc[4 + rr][2 + jj] = __builtin_amdgcn_mfma_f32_16x16x32_f16(a[rr * 2 + kk], b1[jj * 2 + kk], acc[4 + rr][2 + jj], 0, 0, 0);
    __builtin_amdgcn_s_setprio(0);
    if (stA) {
      if (stB) { asm volatile("s_waitcnt vmcnt(4)" ::: "memory"); }   // A(t+1) done
      else     { asm volatile("s_waitcnt vmcnt(0)" ::: "memory"); }   // tail
    }
    __builtin_amdgcn_s_barrier();
    __builtin_amdgcn_sched_barrier(0);
  }
#undef STAGE_SLOT

  // ---- epilogue ----
  const int r0 = bm * 256 + wm * 128 + (lane >> 4) * 4;
  const int c0 = bn * 256 + wn * 64 + (lane & 15);
#pragma unroll
  for (int i = 0; i < 8; ++i) {
#pragma unroll
    for (int j = 0; j < 4; ++j) {
#pragma unroll
      for (int ii = 0; ii < 4; ++ii) {
        const long idx = (long)(r0 + i * 16 + ii) * N + (c0 + j * 16);
        if (EPI == 0) {
          GH[idx] = (_Float16)acc[i][j][ii];
        } else if (EPI == 1) {
          float u = acc[i][j][ii];
          float g = (float)GH[idx];
          GH[idx] = (_Float16)(g / (1.0f + __expf(-g)) * u);
        } else {
          OUT[idx] = acc[i][j][ii];
        }
      }
    }
  }
}

extern "C" void kernel_launch(void* const* d_in, const int* in_sizes, int n_in,
                              void* d_out, int out_size, void* d_ws, size_t ws_size,
                              hipStream_t stream) {
  const float* x           = (const float*)d_in[0];
  const int*   gate_codes  = (const int*)d_in[1];
  const float* gate_scales = (const float*)d_in[2];
  const int*   up_codes    = (const int*)d_in[3];
  const float* up_scales   = (const float*)d_in[4];
  const int*   down_codes  = (const int*)d_in[5];
  const float* down_scales = (const float*)d_in[6];
  float* out = (float*)d_out;

  const long T = 8192, HD = 4096, M = 11008;

  // ws layout (fp16): x16 [T,HD] 67MB | W [M,HD] 90MB (reused 3x) | gh [T,M] 180MB
  char* ws = (char*)d_ws;
  _Float16* x16 = (_Float16*)ws;
  _Float16* W   = (_Float16*)(ws + T * HD * 2);
  _Float16* gh  = (_Float16*)(ws + T * HD * 2 + M * HD * 2);

  cvt_f32_to_f16<<<2048, 256, 0, stream>>>(x, x16, (int)(T * HD / 8));

  // gate: g = x @ Wg^T  -> gh (f16)
  dequant_nf4<<<2048, 256, 0, stream>>>(gate_codes, gate_scales, W,
                                        (int)(M * HD / 8), (int)HD, (int)(HD / 64));
  gemm256<4096, 11008, 0><<<(8192 / 256) * (11008 / 256), 512, 0, stream>>>(
      x16, W, gh, nullptr);

  // up + SwiGLU: gh = silu(gh) * (x @ Wu^T)   (in-place, element-exclusive)
  dequant_nf4<<<2048, 256, 0, stream>>>(up_codes, up_scales, W,
                                        (int)(M * HD / 8), (int)HD, (int)(HD / 64));
  gemm256<4096, 11008, 1><<<(8192 / 256) * (11008 / 256), 512, 0, stream>>>(
      x16, W, gh, nullptr);

  // down: out = gh @ Wd^T  (f32)
  dequant_nf4<<<2048, 256, 0, stream>>>(down_codes, down_scales, W,
                                        (int)(HD * M / 8), (int)M, (int)(M / 64));
  gemm256<11008, 4096, 2><<<(8192 / 256) * (4096 / 256), 512, 0, stream>>>(
      gh, W, nullptr, out);
}

// Round 7
// 2303.795 us; speedup vs baseline: 1.0777x; 1.0777x over previous
//
#include <hip/hip_runtime.h>
#include <hip/hip_bf16.h>

typedef _Float16 half8 __attribute__((ext_vector_type(8)));
typedef float floatx4 __attribute__((ext_vector_type(4)));

__device__ __constant__ float NF4_TAB[16] = {
    -1.0f, -0.6961928009986877f, -0.5250730514526367f, -0.39491748809814453f,
    -0.28444138169288635f, -0.18477343022823334f, -0.09105003625154495f, 0.0f,
    0.07958029955625534f, 0.16093020141124725f, 0.24611230194568634f,
    0.33791524171829224f, 0.44070982933044434f, 0.5626170039176941f,
    0.7229568362236023f, 1.0f};

typedef __attribute__((address_space(3))) void lds_t;
typedef __attribute__((address_space(1))) void gbl_t;

__device__ __forceinline__ void gload16(const void* g, void* l) {
  __builtin_amdgcn_global_load_lds((gbl_t*)g, (lds_t*)l, 16, 0, 0);
}

// ---------------- x f32 -> f16 ----------------
__global__ void cvt_f32_to_f16(const float* __restrict__ in,
                               _Float16* __restrict__ out, int total8) {
  int stride = gridDim.x * blockDim.x;
  for (int i = blockIdx.x * blockDim.x + threadIdx.x; i < total8; i += stride) {
    long e = (long)i * 8;
    const float4* ip = reinterpret_cast<const float4*>(in + e);
    float4 a = ip[0], b = ip[1];
    half8 o;
    o[0] = (_Float16)a.x; o[1] = (_Float16)a.y;
    o[2] = (_Float16)a.z; o[3] = (_Float16)a.w;
    o[4] = (_Float16)b.x; o[5] = (_Float16)b.y;
    o[6] = (_Float16)b.z; o[7] = (_Float16)b.w;
    *reinterpret_cast<half8*>(out + e) = o;
  }
}

// ---------------- NF4 dequant: codes[R,C] + scales[R,C/64] -> f16 [R,C] ----
__global__ void dequant_nf4(const int* __restrict__ codes,
                            const float* __restrict__ scales,
                            _Float16* __restrict__ out,
                            int total8, int C, int CB) {
  __shared__ float lut[16];
  if (threadIdx.x < 16) lut[threadIdx.x] = NF4_TAB[threadIdx.x];
  __syncthreads();
  int stride = gridDim.x * blockDim.x;
  for (int i = blockIdx.x * blockDim.x + threadIdx.x; i < total8; i += stride) {
    long e = (long)i * 8;
    int row = (int)(e / C);
    int col = (int)(e - (long)row * C);
    float sc = scales[row * CB + (col >> 6)];
    const int4* cp = reinterpret_cast<const int4*>(codes + e);
    int4 c0 = cp[0];
    int4 c1 = cp[1];
    half8 o;
    o[0] = (_Float16)(lut[c0.x & 15] * sc);
    o[1] = (_Float16)(lut[c0.y & 15] * sc);
    o[2] = (_Float16)(lut[c0.z & 15] * sc);
    o[3] = (_Float16)(lut[c0.w & 15] * sc);
    o[4] = (_Float16)(lut[c1.x & 15] * sc);
    o[5] = (_Float16)(lut[c1.y & 15] * sc);
    o[6] = (_Float16)(lut[c1.z & 15] * sc);
    o[7] = (_Float16)(lut[c1.w & 15] * sc);
    *reinterpret_cast<half8*>(out + e) = o;
  }
}

// =====================================================================
// 256x256 GEMM, BK=64, 8 waves (2Mx4N), per-wave 128x64 output.
// R5 skeleton (proven ledger) WITHOUT scheduler pins: no sched_barrier(0),
// no explicit lgkmcnt(0) drains. Raw s_barrier + zero-cost compiler fence
// (asm volatile "" memory) at each barrier; compiler inserts fine-grained
// lgkmcnt between ds_read and MFMA (m97 behavior, m141: pins cost ~40%).
// Double-buffered LDS (2 x 32 KB-tile buffers); slabs per buffer:
//   A@kk0 (0), A@kk1 (8192), B@kk0 (16384), B@kk1 (24576)  [f16 units]
// 4 phases/K-tile, 16 MFMA each; one stage slot (2 gloads) per phase:
//   P0->A0(t+1), P1->B0(t+1), P2->A1(t+1), P3->B1(t+1)
// Ledger (vmcnt, 2 loads/slot, never 0 mid-loop):
//   P1: vmcnt(4) certifies A1,B1(t); P3: vmcnt(4) certifies A0,B0(t+1).
// Chunk-XOR swizzle (phys = logical ^ ((row>>1)&3)): 0 bank conflicts.
// EPI: 0 = f16 store; 1 = GH[idx]=silu(GH[idx])*acc (in-place); 2 = f32.
// =====================================================================
#define FENCE() asm volatile("" ::: "memory")

template <int K, int N, int EPI>
__global__ __launch_bounds__(512, 2) void gemm256(
    const _Float16* __restrict__ A,
    const _Float16* __restrict__ B,
    _Float16* __restrict__ GH,
    float* __restrict__ OUT) {
  constexpr int NT = K / 64;
  constexpr int NBC = N / 256;
  constexpr int NWG = (8192 / 256) * NBC;
  __shared__ __align__(16) _Float16 lds[2 * 32768];  // 128 KB

  const int t = threadIdx.x;       // 0..511
  const int lane = t & 63;
  const int wave = t >> 6;
  const int wm = wave >> 2;        // 0..1
  const int wn = wave & 3;         // 0..3

  // XCD-bijective swizzle (NWG % 8 == 0 for both instantiations)
  int bid = blockIdx.x;
  bid = (bid & 7) * (NWG >> 3) + (bid >> 3);
  const int bm = bid / NBC, bn = bid % NBC;

  // staging: round r in {0,1}: row=(t>>2)+128r, chunk lc=(t&3)^((t>>3)&3)
  const int lc = (t & 3) ^ ((t >> 3) & 3);
  const _Float16* gA = A + ((long)bm * 256 + (t >> 2)) * K + lc * 8;
  const _Float16* gB = B + ((long)bn * 256 + (t >> 2)) * K + lc * 8;
  const long rstep = (long)128 * K;
  const int dst = t * 8;  // f16 units; +4096 for round 1 (wave-linear)

  // fragment read offsets (f16 units within buffer)
  const int rA = wm * 128 + (lane & 15);
  const int rB = wn * 64 + (lane & 15);
  const int ckA = ((lane >> 4) ^ ((rA >> 1) & 3)) * 8;  // h(r+16i)==h(r)
  const int ckB = ((lane >> 4) ^ ((rB >> 1) & 3)) * 8;
  const int offA = rA * 32 + ckA;           // + i*512 (+8192 for kk1)
  const int offB = 16384 + rB * 32 + ckB;   // + j*512 (+8192 for kk1)

#define STAGE_SLOT(gp, slab, koff, dbuf)                                   \
  gload16((gp) + (koff), lds + (dbuf) * 32768 + (slab) + dst);             \
  gload16((gp) + (koff) + rstep, lds + (dbuf) * 32768 + (slab) + dst + 4096);

  // ---- prologue: stage tile 0 -> buf0, order A0,B0,A1,B1 ----
  STAGE_SLOT(gA, 0, 0, 0);
  STAGE_SLOT(gB, 16384, 0, 0);
  STAGE_SLOT(gA, 8192, 32, 0);
  STAGE_SLOT(gB, 24576, 32, 0);
  gA += 64; gB += 64;
  asm volatile("s_waitcnt vmcnt(4)" ::: "memory");  // A0,B0(0) done
  __builtin_amdgcn_s_barrier();
  FENCE();

  floatx4 acc[8][4] = {};

  for (int kt = 0; kt < NT; ++kt) {
    const int cb = kt & 1;
    const int sbuf = cb ^ 1;
    const _Float16* lb = lds + cb * 32768;
    const bool st = (kt + 1 < NT);
    const bool last = (kt == NT - 1);

    half8 a[8], b[2];

    // ---- P0: read a@kk0 x8 + b[0..1]@kk0; stage A0(t+1) ----
#pragma unroll
    for (int i = 0; i < 8; ++i)
      a[i] = *reinterpret_cast<const half8*>(&lb[offA + i * 512]);
    b[0] = *reinterpret_cast<const half8*>(&lb[offB]);
    b[1] = *reinterpret_cast<const half8*>(&lb[offB + 512]);
    if (st) { STAGE_SLOT(gA, 0, 0, sbuf); }
    __builtin_amdgcn_s_barrier();
    FENCE();
    __builtin_amdgcn_s_setprio(1);
#pragma unroll
    for (int i = 0; i < 8; ++i) {
      acc[i][0] = __builtin_amdgcn_mfma_f32_16x16x32_f16(a[i], b[0], acc[i][0], 0, 0, 0);
      acc[i][1] = __builtin_amdgcn_mfma_f32_16x16x32_f16(a[i], b[1], acc[i][1], 0, 0, 0);
    }
    __builtin_amdgcn_s_setprio(0);
    __builtin_amdgcn_s_barrier();
    FENCE();

    // ---- P1: read b[2..3]@kk0; stage B0(t+1); certify A1,B1(t) ----
    b[0] = *reinterpret_cast<const half8*>(&lb[offB + 2 * 512]);
    b[1] = *reinterpret_cast<const half8*>(&lb[offB + 3 * 512]);
    if (st) { STAGE_SLOT(gB, 16384, 0, sbuf); }
    if (last) { asm volatile("s_waitcnt vmcnt(0)" ::: "memory"); }
    else      { asm volatile("s_waitcnt vmcnt(4)" ::: "memory"); }
    __builtin_amdgcn_s_barrier();
    FENCE();
    __builtin_amdgcn_s_setprio(1);
#pragma unroll
    for (int i = 0; i < 8; ++i) {
      acc[i][2] = __builtin_amdgcn_mfma_f32_16x16x32_f16(a[i], b[0], acc[i][2], 0, 0, 0);
      acc[i][3] = __builtin_amdgcn_mfma_f32_16x16x32_f16(a[i], b[1], acc[i][3], 0, 0, 0);
    }
    __builtin_amdgcn_s_setprio(0);
    __builtin_amdgcn_s_barrier();
    FENCE();

    // ---- P2: read a@kk1 x8 + b[0..1]@kk1; stage A1(t+1) ----
#pragma unroll
    for (int i = 0; i < 8; ++i)
      a[i] = *reinterpret_cast<const half8*>(&lb[8192 + offA + i * 512]);
    b[0] = *reinterpret_cast<const half8*>(&lb[8192 + offB]);
    b[1] = *reinterpret_cast<const half8*>(&lb[8192 + offB + 512]);
    if (st) { STAGE_SLOT(gA, 8192, 32, sbuf); }
    __builtin_amdgcn_s_barrier();
    FENCE();
    __builtin_amdgcn_s_setprio(1);
#pragma unroll
    for (int i = 0; i < 8; ++i) {
      acc[i][0] = __builtin_amdgcn_mfma_f32_16x16x32_f16(a[i], b[0], acc[i][0], 0, 0, 0);
      acc[i][1] = __builtin_amdgcn_mfma_f32_16x16x32_f16(a[i], b[1], acc[i][1], 0, 0, 0);
    }
    __builtin_amdgcn_s_setprio(0);
    __builtin_amdgcn_s_barrier();
    FENCE();

    // ---- P3: read b[2..3]@kk1; stage B1(t+1); certify A0,B0(t+1) ----
    b[0] = *reinterpret_cast<const half8*>(&lb[8192 + offB + 2 * 512]);
    b[1] = *reinterpret_cast<const half8*>(&lb[8192 + offB + 3 * 512]);
    if (st) { STAGE_SLOT(gB, 24576, 32, sbuf); gA += 64; gB += 64; }
    if (!last) { asm volatile("s_waitcnt vmcnt(4)" ::: "memory"); }
    __builtin_amdgcn_s_barrier();
    FENCE();
    __builtin_amdgcn_s_setprio(1);
#pragma unroll
    for (int i = 0; i < 8; ++i) {
      acc[i][2] = __builtin_amdgcn_mfma_f32_16x16x32_f16(a[i], b[0], acc[i][2], 0, 0, 0);
      acc[i][3] = __builtin_amdgcn_mfma_f32_16x16x32_f16(a[i], b[1], acc[i][3], 0, 0, 0);
    }
    __builtin_amdgcn_s_setprio(0);
    __builtin_amdgcn_s_barrier();
    FENCE();
  }
#undef STAGE_SLOT

  // ---- epilogue ----
  const int r0 = bm * 256 + wm * 128 + (lane >> 4) * 4;
  const int c0 = bn * 256 + wn * 64 + (lane & 15);
#pragma unroll
  for (int i = 0; i < 8; ++i) {
#pragma unroll
    for (int j = 0; j < 4; ++j) {
#pragma unroll
      for (int ii = 0; ii < 4; ++ii) {
        const long idx = (long)(r0 + i * 16 + ii) * N + (c0 + j * 16);
        if (EPI == 0) {
          GH[idx] = (_Float16)acc[i][j][ii];
        } else if (EPI == 1) {
          float u = acc[i][j][ii];
          float g = (float)GH[idx];
          GH[idx] = (_Float16)(g / (1.0f + __expf(-g)) * u);
        } else {
          OUT[idx] = acc[i][j][ii];
        }
      }
    }
  }
}

extern "C" void kernel_launch(void* const* d_in, const int* in_sizes, int n_in,
                              void* d_out, int out_size, void* d_ws, size_t ws_size,
                              hipStream_t stream) {
  const float* x           = (const float*)d_in[0];
  const int*   gate_codes  = (const int*)d_in[1];
  const float* gate_scales = (const float*)d_in[2];
  const int*   up_codes    = (const int*)d_in[3];
  const float* up_scales   = (const float*)d_in[4];
  const int*   down_codes  = (const int*)d_in[5];
  const float* down_scales = (const float*)d_in[6];
  float* out = (float*)d_out;

  const long T = 8192, HD = 4096, M = 11008;

  // ws layout (fp16): x16 [T,HD] 67MB | W [M,HD] 90MB (reused 3x) | gh [T,M] 180MB
  char* ws = (char*)d_ws;
  _Float16* x16 = (_Float16*)ws;
  _Float16* W   = (_Float16*)(ws + T * HD * 2);
  _Float16* gh  = (_Float16*)(ws + T * HD * 2 + M * HD * 2);

  cvt_f32_to_f16<<<2048, 256, 0, stream>>>(x, x16, (int)(T * HD / 8));

  // gate: g = x @ Wg^T  -> gh (f16)
  dequant_nf4<<<2048, 256, 0, stream>>>(gate_codes, gate_scales, W,
                                        (int)(M * HD / 8), (int)HD, (int)(HD / 64));
  gemm256<4096, 11008, 0><<<(8192 / 256) * (11008 / 256), 512, 0, stream>>>(
      x16, W, gh, nullptr);

  // up + SwiGLU: gh = silu(gh) * (x @ Wu^T)   (in-place, element-exclusive)
  dequant_nf4<<<2048, 256, 0, stream>>>(up_codes, up_scales, W,
                                        (int)(M * HD / 8), (int)HD, (int)(HD / 64));
  gemm256<4096, 11008, 1><<<(8192 / 256) * (11008 / 256), 512, 0, stream>>>(
      x16, W, gh, nullptr);

  // down: out = gh @ Wd^T  (f32)
  dequant_nf4<<<2048, 256, 0, stream>>>(down_codes, down_scales, W,
                                        (int)(HD * M / 8), (int)M, (int)(M / 64));
  gemm256<11008, 4096, 2><<<(8192 / 256) * (4096 / 256), 512, 0, stream>>>(
      gh, W, nullptr, out);
}